// Round 3
// baseline (222.245 us; speedup 1.0000x reference)
//
#include <hip/hip_runtime.h>

#define DIM 64
#define MAXBUCK 2560
#define SORT_T 1024

// ---- single-block counting sort by m2>>7 (buckets in LDS) ----
__global__ __launch_bounds__(1024) void k_sort(const int* __restrict__ m2,
                                               int* __restrict__ perm, int N, int nbuck)
{
    __shared__ int cnt[MAXBUCK];
    __shared__ int s[SORT_T];
    const int tid = threadIdx.x;

    for (int i = tid; i < nbuck; i += SORT_T) cnt[i] = 0;
    __syncthreads();
    for (int i = tid; i < N; i += SORT_T) atomicAdd(&cnt[m2[i] >> 7], 1);
    __syncthreads();

    // exclusive scan over nbuck (<= 3*1024) entries
    const int base = tid * 3;
    int loc[3];
    int sum = 0;
    #pragma unroll
    for (int u = 0; u < 3; ++u) {
        const int idx = base + u;
        const int v = (idx < nbuck) ? cnt[idx] : 0;
        loc[u] = sum;
        sum += v;
    }
    s[tid] = sum;
    __syncthreads();
    for (int off = 1; off < SORT_T; off <<= 1) {
        const int v = (tid >= off) ? s[tid - off] : 0;
        __syncthreads();
        s[tid] += v;
        __syncthreads();
    }
    const int excl = (tid > 0) ? s[tid - 1] : 0;
    #pragma unroll
    for (int u = 0; u < 3; ++u) {
        const int idx = base + u;
        if (idx < nbuck) cnt[idx] = excl + loc[u];
    }
    __syncthreads();
    for (int i = tid; i < N; i += SORT_T) {
        const int pos = atomicAdd(&cnt[m2[i] >> 7], 1);
        perm[pos] = i;
    }
}

// ---- main: one WAVE per match, 4 matches per block, XCD-sliced walk ----
__global__ __launch_bounds__(256) void pixel_ap_main(
    const float* __restrict__ d1, const float* __restrict__ d2,
    const float* __restrict__ qw, const float* __restrict__ qb,
    const int* __restrict__ m1, const int* __restrict__ m2,
    const int* __restrict__ offs, const int* __restrict__ perm,
    float* __restrict__ partial, int P, int NEG, int NQ2, int N)
{
    const int tid  = threadIdx.x;
    const int wave = tid >> 6;
    const int lane = tid & 63;
    const int nq   = NQ2 >> 1;
    const int M    = NEG + 1;          // 81 scores

    __shared__ int   s_off[128];
    __shared__ float s_scores[4][96];

    if (tid < NEG) s_off[tid] = offs[tid];
    __syncthreads();

    // XCD-aware: block b lands on XCD b%8; give each XCD a contiguous
    // slice of the sorted match order so its 4 MB L2 holds the window.
    const int b    = blockIdx.x;
    const int per  = (gridDim.x + 7) >> 3;           // blocks per XCD slice
    const int pos  = (b & 7) * per + (b >> 3);
    const int sid0 = pos * 4 + wave;                 // slot in sorted order
    const int sid  = min(sid0, N - 1);

    const int n  = perm[sid];
    const int i1 = m1[n];
    const int i2 = m2[n];

    const int g = lane >> 4;           // score-group 0..3 within wave
    const int l = lane & 15;           // 16 lanes x float4 = 256 B per row
    const float4 a4 = ((const float4*)(d1 + (size_t)i1 * DIM))[l];

    // 81 scores in 3 chunks of 7 iterations: j = g + 4*t, t = 7*c+u
    for (int c = 0; c < 3; ++c) {
        float4 bv[7];
        #pragma unroll
        for (int u = 0; u < 7; ++u) {
            const int j = g + 4 * (7 * c + u);
            if (j < M) {
                const int row = (j == 0) ? i2 : min(i2 + s_off[j - 1], P - 1);
                bv[u] = ((const float4*)(d2 + (size_t)row * DIM))[l];
            }
        }
        #pragma unroll
        for (int u = 0; u < 7; ++u) {
            const int j = g + 4 * (7 * c + u);
            if (j < M) {
                float sd = bv[u].x * a4.x + bv[u].y * a4.y + bv[u].z * a4.z + bv[u].w * a4.w;
                sd += __shfl_xor(sd, 1);
                sd += __shfl_xor(sd, 2);
                sd += __shfl_xor(sd, 4);
                sd += __shfl_xor(sd, 8);
                if (l == 0) s_scores[wave][j] = sd;
            }
        }
    }
    __syncthreads();   // guarantees LDS visibility (cheap; 2 barriers total)

    // ---- hat-basis AP epilogue (validated exact in R2) ----
    const float a_scale = qw[nq];               // +a
    const float amn     = qb[nq - 1] - 1.0f;    // a*mn
    const float ulim    = (float)(nq - 1);

    const float xp = s_scores[wave][0];
    const float up = fminf(fmaxf(a_scale * xp - amn, 0.0f), ulim);
    const float ip = floorf(up);
    const float fp = up - ip;

    float n1 = 0.0f, n2 = 0.0f;
    if (lane < M) {
        const float x  = s_scores[wave][lane];
        const float u  = fminf(fmaxf(a_scale * x - amn, 0.0f), ulim);
        const float fi = floorf(u);
        const float f  = u - fi;
        n2 += (fi >= ip)        ? 1.0f : ((fi == ip - 1.0f) ? f : 0.0f);
        n1 += (fi >= ip + 1.0f) ? 1.0f : ((fi == ip)        ? f : 0.0f);
    }
    const int j2 = lane + 64;
    if (j2 < M) {
        const float x  = s_scores[wave][j2];
        const float u  = fminf(fmaxf(a_scale * x - amn, 0.0f), ulim);
        const float fi = floorf(u);
        const float f  = u - fi;
        n2 += (fi >= ip)        ? 1.0f : ((fi == ip - 1.0f) ? f : 0.0f);
        n1 += (fi >= ip + 1.0f) ? 1.0f : ((fi == ip)        ? f : 0.0f);
    }
    #pragma unroll
    for (int off = 32; off >= 1; off >>= 1) {
        n1 += __shfl_xor(n1, off);
        n2 += __shfl_xor(n2, off);
    }
    if (lane == 0 && sid0 < N) {
        const float ap = fp * fp / (1e-16f + n1) + (1.0f - fp) / (1e-16f + n2);
        partial[n] = 1.0f - ap;
    }
}

// ---- single-block final reduction ----
__global__ __launch_bounds__(1024) void k_reduce(const float* __restrict__ partial,
                                                 float* __restrict__ out, int N)
{
    float s = 0.0f;
    for (int i = threadIdx.x; i < N; i += 1024) s += partial[i];
    #pragma unroll
    for (int off = 32; off >= 1; off >>= 1) s += __shfl_xor(s, off);
    __shared__ float sw[16];
    if ((threadIdx.x & 63) == 0) sw[threadIdx.x >> 6] = s;
    __syncthreads();
    if (threadIdx.x == 0) {
        float t = 0.0f;
        #pragma unroll
        for (int w = 0; w < 16; ++w) t += sw[w];
        out[0] = t / (float)N;
    }
}

extern "C" void kernel_launch(void* const* d_in, const int* in_sizes, int n_in,
                              void* d_out, int out_size, void* d_ws, size_t ws_size,
                              hipStream_t stream) {
    const float* d1   = (const float*)d_in[0];
    const float* d2   = (const float*)d_in[1];
    const float* qw   = (const float*)d_in[2];
    const float* qb   = (const float*)d_in[3];
    const int*   m1   = (const int*)d_in[4];
    const int*   m2   = (const int*)d_in[5];
    const int*   offs = (const int*)d_in[6];

    const int N     = in_sizes[4];
    const int P     = in_sizes[0] / DIM;
    const int NEG   = in_sizes[6];
    const int NQ2   = in_sizes[2];
    const int nbuck = (P + 127) >> 7;

    int*   perm    = (int*)d_ws;
    float* partial = (float*)(perm + N);

    k_sort<<<1, SORT_T, 0, stream>>>(m2, perm, N, nbuck);

    const int nb = (N + 3) / 4;        // 4 matches (waves) per block
    pixel_ap_main<<<nb, 256, 0, stream>>>(d1, d2, qw, qb, m1, m2, offs, perm,
                                          partial, P, NEG, NQ2, N);

    k_reduce<<<1, 1024, 0, stream>>>(partial, (float*)d_out, N);
}

// Round 4
// 210.232 us; speedup vs baseline: 1.0571x; 1.0571x over previous
//
#include <hip/hip_runtime.h>

#define DIM 64
#define MAXBUCK 2560
#define SORT_T 1024

// ---- single-block counting sort by m2>>7 (buckets in LDS) ----
__global__ __launch_bounds__(1024) void k_sort(const int* __restrict__ m2,
                                               int* __restrict__ perm, int N, int nbuck)
{
    __shared__ int cnt[MAXBUCK];
    __shared__ int s[SORT_T];
    const int tid = threadIdx.x;

    for (int i = tid; i < nbuck; i += SORT_T) cnt[i] = 0;
    __syncthreads();
    for (int i = tid; i < N; i += SORT_T) atomicAdd(&cnt[m2[i] >> 7], 1);
    __syncthreads();

    const int base = tid * 3;
    int loc[3];
    int sum = 0;
    #pragma unroll
    for (int u = 0; u < 3; ++u) {
        const int idx = base + u;
        const int v = (idx < nbuck) ? cnt[idx] : 0;
        loc[u] = sum;
        sum += v;
    }
    s[tid] = sum;
    __syncthreads();
    for (int off = 1; off < SORT_T; off <<= 1) {
        const int v = (tid >= off) ? s[tid - off] : 0;
        __syncthreads();
        s[tid] += v;
        __syncthreads();
    }
    const int excl = (tid > 0) ? s[tid - 1] : 0;
    #pragma unroll
    for (int u = 0; u < 3; ++u) {
        const int idx = base + u;
        if (idx < nbuck) cnt[idx] = excl + loc[u];
    }
    __syncthreads();
    for (int i = tid; i < N; i += SORT_T) {
        const int pos = atomicAdd(&cnt[m2[i] >> 7], 1);
        perm[pos] = i;
    }
}

// ---- main: one block (256 thr) per match; 32 groups of 8 lanes;
//      XCD-sliced walk of the sorted order ----
__global__ __launch_bounds__(256) void pixel_ap_main(
    const float* __restrict__ d1, const float* __restrict__ d2,
    const float* __restrict__ qw, const float* __restrict__ qb,
    const int* __restrict__ m1, const int* __restrict__ m2,
    const int* __restrict__ offs, const int* __restrict__ perm,
    float* __restrict__ partial, int P, int NEG, int NQ2, int N)
{
    const int tid = threadIdx.x;
    const int nq  = NQ2 >> 1;
    const int M   = NEG + 1;          // 81 scores

    __shared__ int   s_row[96];
    __shared__ float s_scores[96];
    __shared__ float s_red[8];

    // XCD-aware contiguous slice of sorted order (block b -> XCD b%8)
    const int b   = blockIdx.x;
    const int per = (gridDim.x + 7) >> 3;
    int pos = (b & 7) * per + (b >> 3);
    if (pos >= N) pos = N - 1;        // duplicate work is benign (same value)

    const int n  = perm[pos];
    const int i1 = m1[n];
    const int i2 = m2[n];

    if (tid < M) {
        s_row[tid] = (tid == 0) ? i2 : min(i2 + offs[tid - 1], P - 1);
    }
    __syncthreads();

    const int g  = tid >> 3;          // group 0..31, one score per pass
    const int sl = tid & 7;           // 8 lanes x 32 B = 256 B per row

    const float* a_ptr = d1 + (size_t)i1 * DIM + 8 * sl;
    const float4 a0 = ((const float4*)a_ptr)[0];
    const float4 a1 = ((const float4*)a_ptr)[1];

    // rows for all 3 passes, then all 6 loads in flight, then math
    int rows[3];
    #pragma unroll
    for (int t = 0; t < 3; ++t) {
        const int j = g + 32 * t;
        rows[t] = s_row[(j < M) ? j : 0];
    }
    float4 b0[3], b1[3];
    #pragma unroll
    for (int t = 0; t < 3; ++t) {
        const int j = g + 32 * t;
        if (j < M) {
            const float* p = d2 + (size_t)rows[t] * DIM + 8 * sl;
            b0[t] = ((const float4*)p)[0];
            b1[t] = ((const float4*)p)[1];
        }
    }
    #pragma unroll
    for (int t = 0; t < 3; ++t) {
        const int j = g + 32 * t;
        if (j < M) {
            float s = b0[t].x * a0.x + b0[t].y * a0.y + b0[t].z * a0.z + b0[t].w * a0.w
                    + b1[t].x * a1.x + b1[t].y * a1.y + b1[t].z * a1.z + b1[t].w * a1.w;
            s += __shfl_xor(s, 1);
            s += __shfl_xor(s, 2);
            s += __shfl_xor(s, 4);
            if (sl == 0) s_scores[j] = s;
        }
    }
    __syncthreads();

    // ---- hat-basis AP epilogue (exact; validated R2/R3) ----
    const float a_scale = qw[nq];               // +a
    const float amn     = qb[nq - 1] - 1.0f;    // a*mn
    const float ulim    = (float)(nq - 1);

    const float xp = s_scores[0];
    const float up = fminf(fmaxf(a_scale * xp - amn, 0.0f), ulim);
    const float ip = floorf(up);
    const float fp = up - ip;

    float n1 = 0.0f, n2 = 0.0f;
    if (tid < M) {
        const float x  = s_scores[tid];
        const float u  = fminf(fmaxf(a_scale * x - amn, 0.0f), ulim);
        const float fi = floorf(u);
        const float f  = u - fi;
        n2 = (fi >= ip)        ? 1.0f : ((fi == ip - 1.0f) ? f : 0.0f);
        n1 = (fi >= ip + 1.0f) ? 1.0f : ((fi == ip)        ? f : 0.0f);
    }
    #pragma unroll
    for (int off = 32; off >= 1; off >>= 1) {
        n1 += __shfl_xor(n1, off);
        n2 += __shfl_xor(n2, off);
    }
    const int wid = tid >> 6;
    if ((tid & 63) == 0) { s_red[wid] = n1; s_red[4 + wid] = n2; }
    __syncthreads();
    if (tid == 0) {
        const float N1 = s_red[0] + s_red[1] + s_red[2] + s_red[3];
        const float N2 = s_red[4] + s_red[5] + s_red[6] + s_red[7];
        const float ap = fp * fp / (1e-16f + N1) + (1.0f - fp) / (1e-16f + N2);
        partial[n] = 1.0f - ap;
    }
}

// ---- single-block final reduction ----
__global__ __launch_bounds__(1024) void k_reduce(const float* __restrict__ partial,
                                                 float* __restrict__ out, int N)
{
    float s = 0.0f;
    for (int i = threadIdx.x; i < N; i += 1024) s += partial[i];
    #pragma unroll
    for (int off = 32; off >= 1; off >>= 1) s += __shfl_xor(s, off);
    __shared__ float sw[16];
    if ((threadIdx.x & 63) == 0) sw[threadIdx.x >> 6] = s;
    __syncthreads();
    if (threadIdx.x == 0) {
        float t = 0.0f;
        #pragma unroll
        for (int w = 0; w < 16; ++w) t += sw[w];
        out[0] = t / (float)N;
    }
}

extern "C" void kernel_launch(void* const* d_in, const int* in_sizes, int n_in,
                              void* d_out, int out_size, void* d_ws, size_t ws_size,
                              hipStream_t stream) {
    const float* d1   = (const float*)d_in[0];
    const float* d2   = (const float*)d_in[1];
    const float* qw   = (const float*)d_in[2];
    const float* qb   = (const float*)d_in[3];
    const int*   m1   = (const int*)d_in[4];
    const int*   m2   = (const int*)d_in[5];
    const int*   offs = (const int*)d_in[6];

    const int N     = in_sizes[4];
    const int P     = in_sizes[0] / DIM;
    const int NEG   = in_sizes[6];
    const int NQ2   = in_sizes[2];
    const int nbuck = (P + 127) >> 7;

    int*   perm    = (int*)d_ws;
    float* partial = (float*)(perm + N);

    k_sort<<<1, SORT_T, 0, stream>>>(m2, perm, N, nbuck);

    pixel_ap_main<<<N, 256, 0, stream>>>(d1, d2, qw, qb, m1, m2, offs, perm,
                                         partial, P, NEG, NQ2, N);

    k_reduce<<<1, 1024, 0, stream>>>(partial, (float*)d_out, N);
}